// Round 10
// baseline (370.196 us; speedup 1.0000x reference)
//
#include <hip/hip_runtime.h>
#include <hip/hip_bf16.h>
#include <hip/hip_fp16.h>

typedef short    bf16x8 __attribute__((ext_vector_type(8)));
typedef _Float16 f16x8  __attribute__((ext_vector_type(8)));
typedef __fp16   hw2    __attribute__((ext_vector_type(2)));
typedef float    f32x4  __attribute__((ext_vector_type(4)));

#define DEVI __device__ __forceinline__

static constexpr int    NSAMP = 16384;
static constexpr int    TDIM  = 480;
static constexpr int    KTOT  = 21504;

// ---- workspace layout (bytes) ----
static constexpr size_t SZ_B   = (size_t)KTOT * 64 * 2;            // 2,752,512
static constexpr size_t O_GWS  = 0;                                // 31,457,280
static constexpr size_t O_BFWD = 0;                                // aliases gws (dead before k_bwd)
static constexpr size_t O_HPRE = O_BFWD + SZ_B;                    // f32 [4][N][64], aliases gws
static constexpr size_t O_BBWD = (size_t)TDIM * NSAMP * 4;         // after gws
static constexpr size_t O_DH   = O_BBWD + SZ_B;                    // bf16 N*64
static constexpr size_t O_W1T  = O_DH   + (size_t)NSAMP*64*2;
static constexpr size_t O_W2T  = O_W1T + (size_t)64*64*4;
static constexpr size_t O_W3T  = O_W2T + (size_t)64*64*4;

DEVI float b2f(unsigned short s) { union { unsigned u; float f; } v; v.u = (unsigned)s << 16; return v.f; }
DEVI unsigned short f2b(float f) { union { __hip_bfloat16 h; unsigned short s; } v; v.h = __float2bfloat16(f); return v.s; }
DEVI unsigned short f2h(float f) { union { __half h; unsigned short s; } v; v.h = __float2half(f); return v.s; }
DEVI float h2f(unsigned short s) { union { unsigned short s; _Float16 h; } v; v.s = s; return (float)v.h; }
DEVI bf16x8 as_bf(uint4 q) { union { uint4 q; bf16x8 v; } u; u.q = q; return u.v; }
DEVI f16x8  as_f16(uint4 q) { union { uint4 q; f16x8 v; } u; u.q = q; return u.v; }
DEVI f32x4 mfma16(bf16x8 a, bf16x8 b, f32x4 c) { return __builtin_amdgcn_mfma_f32_16x16x32_bf16(a, b, c, 0, 0, 0); }
DEVI f32x4 mfma16h(f16x8 a, f16x8 b, f32x4 c)  { return __builtin_amdgcn_mfma_f32_16x16x32_f16 (a, b, c, 0, 0, 0); }
// packed fp16 multiply on raw dwords -> v_pk_mul_f16
DEVI unsigned pkmul(unsigned a, unsigned b) {
  union { unsigned u; __half2 h; } x, y, r;
  x.u = a; y.u = b; r.h = __hmul2(x.h, y.h); return r.u;
}
// packed fp16 fma on raw dwords -> v_pk_fma_f16
DEVI unsigned pkfma(unsigned a, unsigned b, unsigned c) {
  union { unsigned u; __half2 h; } x, y, z, r;
  x.u = a; y.u = b; z.u = c; r.h = __hfma2(x.h, y.h, z.h); return r.u;
}
// pack two f32 -> f16x2 dword (v_cvt_pkrtz_f16_f32, one inst)
DEVI unsigned pk_f16(float a, float b) {
  auto r = __builtin_amdgcn_cvt_pkrtz(a, b);
  union { decltype(r) h; unsigned u; } v;
  v.h = r; return v.u;
}
// v_dot2_f32_f16: c += a.x*b.x + a.y*b.y (f32 accumulate, one inst)
DEVI float fdot2(unsigned a, unsigned b, float c) {
  return __builtin_amdgcn_fdot2(__builtin_bit_cast(hw2, a),
                                __builtin_bit_cast(hw2, b), c, false);
}

template<int R> struct RC;
// STRIDE: legacy flat stride (unused now).  BST: shared fp16 tile stride,
// padded so stride-in-dwords mod 32 = 6/6/22 -> row->bank rotation kills the
// 4-8-way LDS conflicts (R9: conflict counter 8.29M -> 295K).  Rows stay
// 8B-aligned.
template<> struct RC<0> { static constexpr int COLS=128, OFF=0,   BST=140, ROWS=128, NCH=4, NM=1, CBASE=0,   KBASE=0,    OUT=0;   };
template<> struct RC<1> { static constexpr int COLS=192, OFF=128, BST=204, ROWS=64,  NCH=2, NM=3, CBASE=512, KBASE=1024, OUT=128; };
template<> struct RC<2> { static constexpr int COLS=160, OFF=320, BST=172, ROWS=32,  NCH=1, NM=5, CBASE=640, KBASE=1280, OUT=320; };

// ============================================================================
// K0: weight prep.  bfwd is f16 for ALL regions (k_fwd is all-f16-MFMA);
// bbwd stays bf16 (k_bwd's MFMA path is bf16: bbwd x dh).
// ============================================================================
__global__ __launch_bounds__(256) void k_prep(
    const float* __restrict__ W0, const float* __restrict__ W1, const float* __restrict__ W2,
    const float* __restrict__ w1, const float* __restrict__ w2, const float* __restrict__ w3,
    unsigned short* __restrict__ bfwd, unsigned short* __restrict__ bbwd,
    float* __restrict__ w1t, float* __restrict__ w2t, float* __restrict__ w3t)
{
  const int e = blockIdx.x*256 + threadIdx.x;
  const float CA = 0.0068192924f;   // 1/sqrt(21504)
  const float C1 = 0.0039371205f;   // CA/sqrt(3)
  const float C2 = 0.0030496940f;   // CA/sqrt(5)
  if (e < KTOT*64) {
    { // forward B: lane holds B[k=quad*8+j][h=hf*16+col]
      int j = e & 7, lane = (e>>3)&63, hf = (e>>9)&3, chunk = e>>11;
      int k = chunk*32 + (lane>>4)*8 + j;
      int h = hf*16 + (lane&15);
      float v;
      if (k < 16384)      v = CA * W0[(size_t)k*64 + h];
      else if (k < 20480) v = C1 * W1[(size_t)(k-16384)*64 + h];
      else                v = C2 * W2[(size_t)(k-20480)*64 + h];
      bfwd[e] = f2h(v);
    }
    { // backward A (symmetrized): lane holds A[k=kb*16+col][h=kc*32+quad*8+j]
      int j = e & 7, lane = (e>>3)&63, kc = (e>>9)&1, kb = e>>10;
      int k = kb*16 + (lane&15);
      int h = kc*32 + (lane>>4)*8 + j;
      float v;
      if (k < 16384)      { int u=k>>7,    vv=k&127;          v = CA*(W0[(size_t)(u*128+vv)*64+h] + W0[(size_t)(vv*128+u)*64+h]); }
      else if (k < 20480) { int l=k-16384; int u=l>>6, vv=l&63; v = C1*(W1[(size_t)(u*64+vv)*64+h] + W1[(size_t)(vv*64+u)*64+h]); }
      else                { int l=k-20480; int u=l>>5, vv=l&31; v = C2*(W2[(size_t)(u*32+vv)*64+h] + W2[(size_t)(vv*32+u)*64+h]); }
      bbwd[e] = f2b(v);
    }
  }
  if (e < 4096) {
    int i = e>>6, j = e&63;
    w1t[j*64+i] = w1[e]; w2t[j*64+i] = w2[e]; w3t[j*64+i] = w3[e];
  }
}

// ---- shared fp16 tile loader: m-major within row (lx[row][m*V + v]), BST
// padded stride.  Used by BOTH k_fwd and k_bwd (verified in R9 for k_bwd).
template<int R>
DEVI void load_tile_mm(const float* __restrict__ t, int nb, unsigned short* lx)
{
  const int tid = threadIdx.x;
  const int s = tid >> 2, p = tid & 3;
  constexpr int CH = RC<R>::COLS/4;
  constexpr int NM = RC<R>::NM;
  constexpr int V  = RC<R>::COLS/NM;
  const float4* src = reinterpret_cast<const float4*>(t + (size_t)(nb+s)*TDIM + RC<R>::OFF + p*CH);
  unsigned short* row = lx + s*RC<R>::BST;
  const int vbase = p*(CH/NM);
  #pragma unroll
  for (int e4 = 0; e4 < CH/4; ++e4) {
    float4 v = src[e4];
    #pragma unroll
    for (int k = 0; k < 4; ++k) {
      const int f = e4*4 + k;          // flat col within this quarter (const)
      const int m = f % NM;            // compile-time
      float x = k==0?v.x: k==1?v.y: k==2?v.z: v.w;
      row[m*V + vbase + f/NM] = f2h(x);
    }
  }
}

// ============================================================================
// K1 region 0: fp16 packed A-build (v_pk_mul_f16) + f16 MFMA.  BST stride.
// ============================================================================
DEVI void fwd_region0_f16(const unsigned short* lx, const uint4* __restrict__ bf,
                          int slot, int lane, f32x4 (&acc)[4][4])
{
  const int quad = lane>>4, col = lane&15;
  for (int u = slot; u < 128; u += 16) {
    unsigned xu2[4];
    #pragma unroll
    for (int mf = 0; mf < 4; ++mf) {
      unsigned s = lx[(mf*16+col)*RC<0>::BST + u];
      xu2[mf] = s | (s<<16);
    }
    #pragma unroll 1
    for (int c = 0; c < 4; ++c) {
      const int chunk = u*4 + c;
      uint4 bv[4];
      #pragma unroll
      for (int hf = 0; hf < 4; ++hf) bv[hf] = bf[(size_t)(chunk*4 + hf)*64 + lane];
      #pragma unroll
      for (int mf = 0; mf < 4; ++mf) {
        const uint4 xq = *reinterpret_cast<const uint4*>(lx + (mf*16+col)*RC<0>::BST + c*32 + quad*8);
        uint4 afq;
        afq.x = pkmul(xu2[mf], xq.x);
        afq.y = pkmul(xu2[mf], xq.y);
        afq.z = pkmul(xu2[mf], xq.z);
        afq.w = pkmul(xu2[mf], xq.w);
        #pragma unroll
        for (int hf = 0; hf < 4; ++hf)
          acc[mf][hf] = mfma16h(as_f16(afq), as_f16(bv[hf]), acc[mf][hf]);
      }
    }
  }
}

// ============================================================================
// K1 regions 1/2: packed-f16 A-build on the m-major tile.
// afq.jp = sum_m xu2[m] (.) xw[m].jp  via 1 pk_mul + (NM-1) pk_fma per dword.
// Replaces 2*NM fma_mix + 1 cvt_pkrtz per dword (~2x fewer VALU ops).
// dword jp of xw[m] = {x[v=..2jp][m], x[v=..2jp+1][m]} -- same lo/hi pairing
// as the f16 MFMA A-frag expects (mapping identical to the old flat path).
// ============================================================================
template<int R>
DEVI void fwd_region_pk(const unsigned short* lx, const uint4* __restrict__ bf,
                        int slot, int lane, f32x4 (&acc)[4][4])
{
  constexpr int NM = RC<R>::NM;
  constexpr int V  = RC<R>::COLS/NM;
  const int quad = lane>>4, col = lane&15;
  for (int u = slot; u < RC<R>::ROWS; u += 16) {
    unsigned xu2[4][NM];
    #pragma unroll
    for (int mf = 0; mf < 4; ++mf)
      #pragma unroll
      for (int m = 0; m < NM; ++m) {
        unsigned s = lx[(mf*16+col)*RC<R>::BST + m*V + u];
        xu2[mf][m] = s | (s<<16);
      }
    #pragma unroll 1
    for (int c = 0; c < RC<R>::NCH; ++c) {
      const int chunk = RC<R>::CBASE + u*RC<R>::NCH + c;
      uint4 bv[4];
      #pragma unroll
      for (int hf = 0; hf < 4; ++hf) bv[hf] = bf[(size_t)(chunk*4 + hf)*64 + lane];
      #pragma unroll
      for (int mf = 0; mf < 4; ++mf) {
        const unsigned short* rowp = lx + (mf*16+col)*RC<R>::BST;
        uint4 xw[NM];
        #pragma unroll
        for (int m = 0; m < NM; ++m)
          xw[m] = *reinterpret_cast<const uint4*>(rowp + m*V + c*32 + quad*8);
        uint4 afq;
        afq.x = pkmul(xu2[mf][0], xw[0].x);
        afq.y = pkmul(xu2[mf][0], xw[0].y);
        afq.z = pkmul(xu2[mf][0], xw[0].z);
        afq.w = pkmul(xu2[mf][0], xw[0].w);
        #pragma unroll
        for (int m = 1; m < NM; ++m) {
          afq.x = pkfma(xu2[mf][m], xw[m].x, afq.x);
          afq.y = pkfma(xu2[mf][m], xw[m].y, afq.y);
          afq.z = pkfma(xu2[mf][m], xw[m].z, afq.z);
          afq.w = pkfma(xu2[mf][m], xw[m].w, afq.w);
        }
        #pragma unroll
        for (int hf = 0; hf < 4; ++hf)
          acc[mf][hf] = mfma16h(as_f16(afq), as_f16(bv[hf]), acc[mf][hf]);
      }
    }
  }
}

__global__ __launch_bounds__(256,2) void k_fwd(const float* __restrict__ t,
                                               const uint4* __restrict__ bfwd,
                                               float* __restrict__ hpre)
{
  __shared__ __align__(16) unsigned char smem[26112];  // max BST tile (r1: 64*204*2); red[16KB] aliases
  unsigned short* lx = (unsigned short*)smem;
  const int nb = blockIdx.x*64;
  const int wv = threadIdx.x>>6, lane = threadIdx.x&63;
  const int slot = blockIdx.y*4 + wv;
  const int quad = lane>>4, col = lane&15;

  f32x4 acc[4][4];
  #pragma unroll
  for (int a = 0; a < 4; ++a)
    #pragma unroll
    for (int b = 0; b < 4; ++b) acc[a][b] = (f32x4){0.f,0.f,0.f,0.f};

  load_tile_mm<0>(t, nb, lx); __syncthreads();
  fwd_region0_f16(lx, bfwd, slot, lane, acc); __syncthreads();
  load_tile_mm<1>(t, nb, lx); __syncthreads();
  fwd_region_pk<1>(lx, bfwd, slot, lane, acc); __syncthreads();
  load_tile_mm<2>(t, nb, lx); __syncthreads();
  fwd_region_pk<2>(lx, bfwd, slot, lane, acc); __syncthreads();

  float* red = (float*)smem;                 // 64x64 f32 = 16 KB
  for (int tw = 0; tw < 4; ++tw) {
    if (wv == tw) {
      #pragma unroll
      for (int mf = 0; mf < 4; ++mf)
        #pragma unroll
        for (int hf = 0; hf < 4; ++hf)
          #pragma unroll
          for (int rr = 0; rr < 4; ++rr) {
            int idx = (mf*16 + quad*4 + rr)*64 + hf*16 + col;
            if (tw == 0) red[idx] = acc[mf][hf][rr]; else red[idx] += acc[mf][hf][rr];
          }
    }
    __syncthreads();
  }
  float* hp = hpre + (size_t)blockIdx.y*NSAMP*64;
  for (int i = threadIdx.x; i < 4096; i += 256)
    hp[(size_t)(nb + (i>>6))*64 + (i&63)] = red[i];
}

// ============================================================================
// K2: MLP fwd + bwd.  16 samples/block, 1024 blocks.
// ============================================================================
__global__ __launch_bounds__(256) void k_mlp(
    const float* __restrict__ hpre,
    const float* __restrict__ w1, const float* __restrict__ b1,
    const float* __restrict__ w2, const float* __restrict__ b2,
    const float* __restrict__ w3, const float* __restrict__ b3,
    const float* __restrict__ w1t, const float* __restrict__ w2t, const float* __restrict__ w3t,
    float* __restrict__ xout, unsigned short* __restrict__ dhb)
{
  constexpr int SB  = 16;          // samples per block
  constexpr int LDW = 68;          // padded row stride (floats)
  __shared__ float Hs [SB*LDW];    // h rows; reused as g1 staging in phase D
  __shared__ float Bh1[SB*LDW];
  __shared__ float Bh2[SB*LDW];
  __shared__ float Bg2[SB*LDW];
  __shared__ unsigned short Bsp1[SB*LDW];
  const int n  = threadIdx.x & 15;       // sample within block
  const int g  = threadIdx.x >> 4;       // j-group [0,16)
  const int jb = g*4;                    // 4 consecutive j's per thread
  const int nb = blockIdx.x*SB;
  const size_t row = (size_t)(nb + n)*64;
  const size_t base = (size_t)nb*64;

  // stage h = sum of 4 hpre slices (SB*64 = 1024 elems, coalesced)
  for (int idx = threadIdx.x; idx < SB*64; idx += 256) {
    float s = hpre[base + idx]
            + hpre[(size_t)NSAMP*64   + base + idx]
            + hpre[(size_t)2*NSAMP*64 + base + idx]
            + hpre[(size_t)3*NSAMP*64 + base + idx];
    Hs[(idx>>6)*LDW + (idx&63)] = s;
  }

  // dh2r[jj] = row-sum of w3 (upstream grad of xout is ones)
  float dh2r[4];
  #pragma unroll
  for (int jj = 0; jj < 4; ++jj) {
    const float4* wr = reinterpret_cast<const float4*>(w3 + (jb+jj)*64);
    float s = 0.f;
    #pragma unroll
    for (int z4 = 0; z4 < 16; ++z4) { float4 v = wr[z4]; s += v.x; s += v.y; s += v.z; s += v.w; }
    dh2r[jj] = s;
  }
  __syncthreads();

  float hrow[64];
  #pragma unroll
  for (int i4 = 0; i4 < 16; ++i4) {
    float4 v = *reinterpret_cast<const float4*>(&Hs[n*LDW + i4*4]);
    hrow[i4*4+0]=v.x; hrow[i4*4+1]=v.y; hrow[i4*4+2]=v.z; hrow[i4*4+3]=v.w;
  }

  // ---- layer 1 fwd ----
  {
    float h1v[4], spv[4];
    #pragma unroll
    for (int jj = 0; jj < 4; ++jj) {
      const int j = jb + jj;
      float a = b1[j];
      const float4* wr = reinterpret_cast<const float4*>(w1t + j*64);
      #pragma unroll
      for (int i4 = 0; i4 < 16; ++i4) {
        float4 wv = wr[i4];
        a += hrow[i4*4+0]*wv.x; a += hrow[i4*4+1]*wv.y;
        a += hrow[i4*4+2]*wv.z; a += hrow[i4*4+3]*wv.w;
      }
      float sg = 1.f/(1.f + __expf(-a));
      h1v[jj] = a*sg;
      spv[jj] = sg*(1.f + a*(1.f-sg));
    }
    float4 o; o.x=h1v[0]; o.y=h1v[1]; o.z=h1v[2]; o.w=h1v[3];
    *reinterpret_cast<float4*>(&Bh1[n*LDW + jb]) = o;
    ushort4 us; us.x=f2b(spv[0]); us.y=f2b(spv[1]); us.z=f2b(spv[2]); us.w=f2b(spv[3]);
    *reinterpret_cast<ushort4*>(&Bsp1[n*LDW + jb]) = us;
  }
  __syncthreads();

  // ---- layer 2 fwd ----
  float h1row[64];
  #pragma unroll
  for (int i4 = 0; i4 < 16; ++i4) {
    float4 v = *reinterpret_cast<const float4*>(&Bh1[n*LDW + i4*4]);
    h1row[i4*4+0]=v.x; h1row[i4*4+1]=v.y; h1row[i4*4+2]=v.z; h1row[i4*4+3]=v.w;
  }
  {
    float h2v[4], g2v[4];
    #pragma unroll
    for (int jj = 0; jj < 4; ++jj) {
      const int j = jb + jj;
      float a = b2[j];
      const float4* wr = reinterpret_cast<const float4*>(w2t + j*64);
      #pragma unroll
      for (int i4 = 0; i4 < 16; ++i4) {
        float4 wv = wr[i4];
        a += h1row[i4*4+0]*wv.x; a += h1row[i4*4+1]*wv.y;
        a += h1row[i4*4+2]*wv.z; a += h1row[i4*4+3]*wv.w;
      }
      float sg = 1.f/(1.f + __expf(-a));
      h2v[jj] = a*sg;
      g2v[jj] = dh2r[jj]*(sg*(1.f + a*(1.f-sg)));
    }
    float4 o; o.x=h2v[0]; o.y=h2v[1]; o.z=h2v[2]; o.w=h2v[3];
    *reinterpret_cast<float4*>(&Bh2[n*LDW + jb]) = o;
    float4 p; p.x=g2v[0]; p.y=g2v[1]; p.z=g2v[2]; p.w=g2v[3];
    *reinterpret_cast<float4*>(&Bg2[n*LDW + jb]) = p;
  }
  __syncthreads();

  // ---- layer 3 fwd ----
  {
    float h2row[64];
    #pragma unroll
    for (int i4 = 0; i4 < 16; ++i4) {
      float4 v = *reinterpret_cast<const float4*>(&Bh2[n*LDW + i4*4]);
      h2row[i4*4+0]=v.x; h2row[i4*4+1]=v.y; h2row[i4*4+2]=v.z; h2row[i4*4+3]=v.w;
    }
    float xo[4];
    #pragma unroll
    for (int jj = 0; jj < 4; ++jj) {
      const int j = jb + jj;
      float a = b3[j];
      const float4* wr = reinterpret_cast<const float4*>(w3t + j*64);
      #pragma unroll
      for (int i4 = 0; i4 < 16; ++i4) {
        float4 wv = wr[i4];
        a += h2row[i4*4+0]*wv.x; a += h2row[i4*4+1]*wv.y;
        a += h2row[i4*4+2]*wv.z; a += h2row[i4*4+3]*wv.w;
      }
      xo[jj] = a;
    }
    float4 o; o.x=xo[0]; o.y=xo[1]; o.z=xo[2]; o.w=xo[3];
    *reinterpret_cast<float4*>(&xout[row + jb]) = o;
  }

  // ---- bwd layer 2: g1 = (g2 @ w2^T) * sp1 ----
  {
    float g2row[64];
    #pragma unroll
    for (int i4 = 0; i4 < 16; ++i4) {
      float4 v = *reinterpret_cast<const float4*>(&Bg2[n*LDW + i4*4]);
      g2row[i4*4+0]=v.x; g2row[i4*4+1]=v.y; g2row[i4*4+2]=v.z; g2row[i4*4+3]=v.w;
    }
    float g1v[4];
    #pragma unroll
    for (int jj = 0; jj < 4; ++jj) {
      const int i = jb + jj;
      float a = 0.f;
      const float4* wr = reinterpret_cast<const float4*>(w2 + i*64);
      #pragma unroll
      for (int z4 = 0; z4 < 16; ++z4) {
        float4 wv = wr[z4];
        a += g2row[z4*4+0]*wv.x; a += g2row[z4*4+1]*wv.y;
        a += g2row[z4*4+2]*wv.z; a += g2row[z4*4+3]*wv.w;
      }
      g1v[jj] = a * b2f(Bsp1[n*LDW + i]);
    }
    float4 o; o.x=g1v[0]; o.y=g1v[1]; o.z=g1v[2]; o.w=g1v[3];
    *reinterpret_cast<float4*>(&Hs[n*LDW + jb]) = o;
  }
  __syncthreads();

  // ---- bwd layer 1: dh = g1 @ w1^T -> dhb (bf16) ----
  {
    float g1row[64];
    #pragma unroll
    for (int i4 = 0; i4 < 16; ++i4) {
      float4 v = *reinterpret_cast<const float4*>(&Hs[n*LDW + i4*4]);
      g1row[i4*4+0]=v.x; g1row[i4*4+1]=v.y; g1row[i4*4+2]=v.z; g1row[i4*4+3]=v.w;
    }
    float dv[4];
    #pragma unroll
    for (int jj = 0; jj < 4; ++jj) {
      const int i = jb + jj;
      float a = 0.f;
      const float4* wr = reinterpret_cast<const float4*>(w1 + i*64);
      #pragma unroll
      for (int z4 = 0; z4 < 16; ++z4) {
        float4 wv = wr[z4];
        a += g1row[z4*4+0]*wv.x; a += g1row[z4*4+1]*wv.y;
        a += g1row[z4*4+2]*wv.z; a += g1row[z4*4+3]*wv.w;
      }
      dv[jj] = a;
    }
    ushort4 us; us.x=f2b(dv[0]); us.y=f2b(dv[1]); us.z=f2b(dv[2]); us.w=f2b(dv[3]);
    *reinterpret_cast<ushort4*>(&dhb[row + jb]) = us;
  }
}

// ============================================================================
// K3: backward TP.  MFMA path (bbwd x dh, both bf16); VALU v-contraction via
// v_dot2_f32_f16 against the m-major BST-padded fp16 x-tile.
// launch_bounds(256,2): tighter bounds spill (R5/R8).
// ============================================================================
template<int R>
DEVI void bwd_region(const unsigned short* lx, const uint4 (&bq)[4][2],
                     const uint4* __restrict__ ba, int slot, int lane,
                     float* __restrict__ gws, int nb)
{
  constexpr int NM = RC<R>::NM;
  constexpr int V  = RC<R>::COLS / NM;   // 128 / 64 / 32
  const int quad = lane>>4, col = lane&15;
  for (int u = slot; u < RC<R>::ROWS; u += 16) {
    float gacc[4][NM];
    #pragma unroll
    for (int nf = 0; nf < 4; ++nf)
      #pragma unroll
      for (int m = 0; m < NM; ++m) gacc[nf][m] = 0.f;

    #pragma unroll 1
    for (int c = 0; c < RC<R>::NCH; ++c) {
      uint4 aq[2][2];
      #pragma unroll
      for (int kf = 0; kf < 2; ++kf)
        #pragma unroll
        for (int kc = 0; kc < 2; ++kc) {
          int kb = RC<R>::KBASE + u*(2*RC<R>::NCH) + c*2 + kf;
          aq[kf][kc] = ba[(size_t)(kb*2+kc)*64 + lane];
        }
      #pragma unroll
      for (int kf = 0; kf < 2; ++kf) {
        const int v0 = c*32 + kf*16 + quad*4;
        #pragma unroll
        for (int nf = 0; nf < 4; ++nf) {
          f32x4 a4 = (f32x4){0.f,0.f,0.f,0.f};
          a4 = mfma16(as_bf(aq[kf][0]), as_bf(bq[nf][0]), a4);
          a4 = mfma16(as_bf(aq[kf][1]), as_bf(bq[nf][1]), a4);
          const unsigned pA = pk_f16(a4[0], a4[1]);   // {a4[0], a4[1]} f16
          const unsigned pB = pk_f16(a4[2], a4[3]);   // {a4[2], a4[3]} f16
          const unsigned short* xp = lx + (nf*16+col)*RC<R>::BST;
          #pragma unroll
          for (int m = 0; m < NM; ++m) {
            const uint2 xw = *reinterpret_cast<const uint2*>(xp + m*V + v0);
            gacc[nf][m] = fdot2(pA, xw.x, fdot2(pB, xw.y, gacc[nf][m]));
          }
        }
      }
    }
    #pragma unroll
    for (int nf = 0; nf < 4; ++nf)
      #pragma unroll
      for (int m = 0; m < NM; ++m) {
        float v = gacc[nf][m];
        v += __shfl_down(v, 32, 64);
        v += __shfl_down(v, 16, 64);
        if (lane < 16)
          gws[(size_t)(RC<R>::OUT + u*NM + m)*NSAMP + nb + nf*16 + lane] = v;
      }
  }
}

__global__ __launch_bounds__(256,2) void k_bwd(const float* __restrict__ t,
                                               const uint4* __restrict__ bbwd,
                                               const unsigned short* __restrict__ dh,
                                               float* __restrict__ gws)
{
  __shared__ __align__(16) unsigned char smem[26112];  // max BST tile (r1: 64*204*2)
  unsigned short* lx = (unsigned short*)smem;
  const int nb = blockIdx.x*64;
  const int wv = threadIdx.x>>6, lane = threadIdx.x&63;
  const int slot = blockIdx.y*4 + wv;
  const int cl = lane&15, qd = lane>>4;

  uint4 bq[4][2];   // resident dh B-frags: B[h][n]
  #pragma unroll
  for (int nf = 0; nf < 4; ++nf)
    #pragma unroll
    for (int kc = 0; kc < 2; ++kc)
      bq[nf][kc] = *reinterpret_cast<const uint4*>(dh + (size_t)(nb + nf*16 + cl)*64 + kc*32 + qd*8);

  load_tile_mm<0>(t, nb, lx); __syncthreads();
  bwd_region<0>(lx, bq, bbwd, slot, lane, gws, nb); __syncthreads();
  load_tile_mm<1>(t, nb, lx); __syncthreads();
  bwd_region<1>(lx, bq, bbwd, slot, lane, gws, nb); __syncthreads();
  load_tile_mm<2>(t, nb, lx); __syncthreads();
  bwd_region<2>(lx, bq, bbwd, slot, lane, gws, nb);
}

// ============================================================================
// K4: transpose gws[480][16384] -> y[16384][480], coalesced both sides.
// ============================================================================
__global__ __launch_bounds__(256) void k_tr(const float* __restrict__ gws,
                                            float* __restrict__ y)
{
  __shared__ float tile[32][481];
  const int n0 = blockIdx.x*32;
  for (int idx = threadIdx.x; idx < 480*8; idx += 256) {
    int c = idx >> 3, i4 = idx & 7;
    float4 v = reinterpret_cast<const float4*>(gws + (size_t)c*NSAMP + n0)[i4];
    tile[i4*4+0][c] = v.x; tile[i4*4+1][c] = v.y;
    tile[i4*4+2][c] = v.z; tile[i4*4+3][c] = v.w;
  }
  __syncthreads();
  for (int idx = threadIdx.x; idx < 32*120; idx += 256) {
    int s = idx/120, c4 = idx%120;
    float4 v = { tile[s][c4*4+0], tile[s][c4*4+1], tile[s][c4*4+2], tile[s][c4*4+3] };
    reinterpret_cast<float4*>(y + (size_t)(n0+s)*TDIM)[c4] = v;
  }
}

// ============================================================================
extern "C" void kernel_launch(void* const* d_in, const int* in_sizes, int n_in,
                              void* d_out, int out_size, void* d_ws, size_t ws_size,
                              hipStream_t stream) {
  (void)in_sizes; (void)n_in; (void)out_size; (void)ws_size;
  const float* t  = (const float*)d_in[0];
  const float* W0 = (const float*)d_in[1];
  const float* W1 = (const float*)d_in[2];
  const float* W2 = (const float*)d_in[3];
  const float* w1 = (const float*)d_in[4];
  const float* b1 = (const float*)d_in[5];
  const float* w2 = (const float*)d_in[6];
  const float* b2 = (const float*)d_in[7];
  const float* w3 = (const float*)d_in[8];
  const float* b3 = (const float*)d_in[9];

  char* ws = (char*)d_ws;
  float*          gws  = (float*)(ws + O_GWS);
  unsigned short* bfwd = (unsigned short*)(ws + O_BFWD);
  unsigned short* bbwd = (unsigned short*)(ws + O_BBWD);
  float*          hpre = (float*)(ws + O_HPRE);
  unsigned short* dhb  = (unsigned short*)(ws + O_DH);
  float*          w1t  = (float*)(ws + O_W1T);
  float*          w2t  = (float*)(ws + O_W2T);
  float*          w3t  = (float*)(ws + O_W3T);

  float* xout = (float*)d_out;
  float* y    = (float*)d_out + (size_t)NSAMP*64;

  k_prep<<<dim3(5376), dim3(256), 0, stream>>>(W0, W1, W2, w1, w2, w3,
                                               bfwd, bbwd, w1t, w2t, w3t);
  k_fwd <<<dim3(256,4), dim3(256), 0, stream>>>(t, (const uint4*)bfwd, hpre);
  k_mlp <<<dim3(1024), dim3(256), 0, stream>>>(hpre, w1, b1, w2, b2, w3, b3,
                                               w1t, w2t, w3t, xout, dhb);
  k_bwd <<<dim3(256,4), dim3(256), 0, stream>>>(t, (const uint4*)bbwd, dhb, gws);
  k_tr  <<<dim3(512),   dim3(256), 0, stream>>>(gws, y);
}

// Round 11
// 313.443 us; speedup vs baseline: 1.1811x; 1.1811x over previous
//
#include <hip/hip_runtime.h>
#include <hip/hip_bf16.h>
#include <hip/hip_fp16.h>

typedef short    bf16x8 __attribute__((ext_vector_type(8)));
typedef _Float16 f16x8  __attribute__((ext_vector_type(8)));
typedef __fp16   hw2    __attribute__((ext_vector_type(2)));
typedef float    f32x4  __attribute__((ext_vector_type(4)));

#define DEVI __device__ __forceinline__

static constexpr int    NSAMP = 16384;
static constexpr int    TDIM  = 480;
static constexpr int    KTOT  = 21504;

// ---- workspace layout (bytes) ----
static constexpr size_t SZ_B   = (size_t)KTOT * 64 * 2;            // 2,752,512
static constexpr size_t O_GWS  = 0;                                // 31,457,280
static constexpr size_t O_BFWD = 0;                                // aliases gws (dead before k_bwd)
static constexpr size_t O_HPRE = O_BFWD + SZ_B;                    // f32 [4][N][64], aliases gws
static constexpr size_t O_BBWD = (size_t)TDIM * NSAMP * 4;         // after gws
static constexpr size_t O_DH   = O_BBWD + SZ_B;                    // bf16 N*64
static constexpr size_t O_W1T  = O_DH   + (size_t)NSAMP*64*2;
static constexpr size_t O_W2T  = O_W1T + (size_t)64*64*4;
static constexpr size_t O_W3T  = O_W2T + (size_t)64*64*4;

DEVI float b2f(unsigned short s) { union { unsigned u; float f; } v; v.u = (unsigned)s << 16; return v.f; }
DEVI unsigned short f2b(float f) { union { __hip_bfloat16 h; unsigned short s; } v; v.h = __float2bfloat16(f); return v.s; }
DEVI unsigned short f2h(float f) { union { __half h; unsigned short s; } v; v.h = __float2half(f); return v.s; }
DEVI float h2f(unsigned short s) { union { unsigned short s; _Float16 h; } v; v.s = s; return (float)v.h; }
DEVI bf16x8 as_bf(uint4 q) { union { uint4 q; bf16x8 v; } u; u.q = q; return u.v; }
DEVI f16x8  as_f16(uint4 q) { union { uint4 q; f16x8 v; } u; u.q = q; return u.v; }
DEVI f32x4 mfma16(bf16x8 a, bf16x8 b, f32x4 c) { return __builtin_amdgcn_mfma_f32_16x16x32_bf16(a, b, c, 0, 0, 0); }
DEVI f32x4 mfma16h(f16x8 a, f16x8 b, f32x4 c)  { return __builtin_amdgcn_mfma_f32_16x16x32_f16 (a, b, c, 0, 0, 0); }
// packed fp16 multiply on raw dwords -> v_pk_mul_f16
DEVI unsigned pkmul(unsigned a, unsigned b) {
  union { unsigned u; __half2 h; } x, y, r;
  x.u = a; y.u = b; r.h = __hmul2(x.h, y.h); return r.u;
}
// pack two f32 -> f16x2 dword (v_cvt_pkrtz_f16_f32, one inst)
DEVI unsigned pk_f16(float a, float b) {
  auto r = __builtin_amdgcn_cvt_pkrtz(a, b);
  union { decltype(r) h; unsigned u; } v;
  v.h = r; return v.u;
}
// v_dot2_f32_f16: c += a.x*b.x + a.y*b.y (f32 accumulate, one inst)
DEVI float fdot2(unsigned a, unsigned b, float c) {
  return __builtin_amdgcn_fdot2(__builtin_bit_cast(hw2, a),
                                __builtin_bit_cast(hw2, b), c, false);
}
// mixed-precision FMA: d = a(f32) * f16half(w) + d  -- one v_fma_mix_f32
// (used in k_fwd only; verified passing there)
DEVI float fmix_lo(float a, unsigned w, float c) {
  float d = c;
  asm("v_fma_mix_f32 %0, %1, %2, %0 op_sel_hi:[0,1,0]" : "+v"(d) : "v"(a), "v"(w));
  return d;
}
DEVI float fmix_hi(float a, unsigned w, float c) {
  float d = c;
  asm("v_fma_mix_f32 %0, %1, %2, %0 op_sel:[0,1,0] op_sel_hi:[0,1,0]" : "+v"(d) : "v"(a), "v"(w));
  return d;
}

// word selector (pure SSA, all indices compile-time after unroll)
template<int NQ>
DEVI unsigned wsel4(const uint4 (&q)[NQ], int wi) {   // wi in [0, 4*NQ)
  const uint4 qq = q[wi>>2];
  const int k = wi&3;
  return k==0?qq.x: k==1?qq.y: k==2?qq.z: qq.w;
}

template<int R> struct RC;
// STRIDE: k_fwd tile stride (flat layout, fma_mix path — R10 showed the
// m-major/pk rewrite regresses k_fwd).  BST: k_bwd tile stride, padded so
// stride-in-dwords mod 32 = 6/6/22 -> row->bank rotation kills the 4-8-way
// LDS conflicts (R9: conflict counter 8.29M -> 295K).  Rows stay 8B-aligned.
template<> struct RC<0> { static constexpr int COLS=128, OFF=0,   STRIDE=136, BST=140, ROWS=128, NCH=4, NM=1, CBASE=0,   KBASE=0,    OUT=0;   };
template<> struct RC<1> { static constexpr int COLS=192, OFF=128, STRIDE=200, BST=204, ROWS=64,  NCH=2, NM=3, CBASE=512, KBASE=1024, OUT=128; };
template<> struct RC<2> { static constexpr int COLS=160, OFF=320, STRIDE=168, BST=172, ROWS=32,  NCH=1, NM=5, CBASE=640, KBASE=1280, OUT=320; };

// ============================================================================
// K0: weight prep.  bfwd is f16 for ALL regions (k_fwd is all-f16-MFMA);
// bbwd stays bf16 (k_bwd's MFMA path is bf16: bbwd x dh).
// ============================================================================
__global__ __launch_bounds__(256) void k_prep(
    const float* __restrict__ W0, const float* __restrict__ W1, const float* __restrict__ W2,
    const float* __restrict__ w1, const float* __restrict__ w2, const float* __restrict__ w3,
    unsigned short* __restrict__ bfwd, unsigned short* __restrict__ bbwd,
    float* __restrict__ w1t, float* __restrict__ w2t, float* __restrict__ w3t)
{
  const int e = blockIdx.x*256 + threadIdx.x;
  const float CA = 0.0068192924f;   // 1/sqrt(21504)
  const float C1 = 0.0039371205f;   // CA/sqrt(3)
  const float C2 = 0.0030496940f;   // CA/sqrt(5)
  if (e < KTOT*64) {
    { // forward B: lane holds B[k=quad*8+j][h=hf*16+col]
      int j = e & 7, lane = (e>>3)&63, hf = (e>>9)&3, chunk = e>>11;
      int k = chunk*32 + (lane>>4)*8 + j;
      int h = hf*16 + (lane&15);
      float v;
      if (k < 16384)      v = CA * W0[(size_t)k*64 + h];
      else if (k < 20480) v = C1 * W1[(size_t)(k-16384)*64 + h];
      else                v = C2 * W2[(size_t)(k-20480)*64 + h];
      bfwd[e] = f2h(v);
    }
    { // backward A (symmetrized): lane holds A[k=kb*16+col][h=kc*32+quad*8+j]
      int j = e & 7, lane = (e>>3)&63, kc = (e>>9)&1, kb = e>>10;
      int k = kb*16 + (lane&15);
      int h = kc*32 + (lane>>4)*8 + j;
      float v;
      if (k < 16384)      { int u=k>>7,    vv=k&127;          v = CA*(W0[(size_t)(u*128+vv)*64+h] + W0[(size_t)(vv*128+u)*64+h]); }
      else if (k < 20480) { int l=k-16384; int u=l>>6, vv=l&63; v = C1*(W1[(size_t)(u*64+vv)*64+h] + W1[(size_t)(vv*64+u)*64+h]); }
      else                { int l=k-20480; int u=l>>5, vv=l&31; v = C2*(W2[(size_t)(u*32+vv)*64+h] + W2[(size_t)(vv*32+u)*64+h]); }
      bbwd[e] = f2b(v);
    }
  }
  if (e < 4096) {
    int i = e>>6, j = e&63;
    w1t[j*64+i] = w1[e]; w2t[j*64+i] = w2[e]; w3t[j*64+i] = w3[e];
  }
}

// ---- cooperative x-tile loader (k_fwd): 64 samples x COLS; fp16 encode ----
template<int R, bool H>
DEVI void load_tile(const float* __restrict__ t, int nb, unsigned short* lx)
{
  const int tid = threadIdx.x;
  const int s = tid >> 2, p = tid & 3;          // row, quarter
  constexpr int CH = RC<R>::COLS/4;             // 32 / 48 / 40
  const float4* src = reinterpret_cast<const float4*>(t + (size_t)(nb+s)*TDIM + RC<R>::OFF + p*CH);
  unsigned short* dst = lx + s*RC<R>::STRIDE + p*CH;
  #pragma unroll
  for (int e4 = 0; e4 < CH/4; ++e4) {
    float4 v = src[e4];
    ushort4 o;
    if (H) { o.x = f2h(v.x); o.y = f2h(v.y); o.z = f2h(v.z); o.w = f2h(v.w); }
    else   { o.x = f2b(v.x); o.y = f2b(v.y); o.z = f2b(v.z); o.w = f2b(v.w); }
    *reinterpret_cast<ushort4*>(dst + e4*4) = o;
  }
}

// ---- k_bwd tile loader, m-major within row, padded BST stride, fp16 ----
template<int R>
DEVI void load_tile_bwd(const float* __restrict__ t, int nb, unsigned short* lx)
{
  const int tid = threadIdx.x;
  const int s = tid >> 2, p = tid & 3;
  constexpr int CH = RC<R>::COLS/4;
  constexpr int NM = RC<R>::NM;
  constexpr int V  = RC<R>::COLS/NM;
  const float4* src = reinterpret_cast<const float4*>(t + (size_t)(nb+s)*TDIM + RC<R>::OFF + p*CH);
  unsigned short* row = lx + s*RC<R>::BST;
  const int vbase = p*(CH/NM);
  #pragma unroll
  for (int e4 = 0; e4 < CH/4; ++e4) {
    float4 v = src[e4];
    #pragma unroll
    for (int k = 0; k < 4; ++k) {
      const int f = e4*4 + k;          // flat col within this quarter (const)
      const int m = f % NM;            // compile-time
      float x = k==0?v.x: k==1?v.y: k==2?v.z: v.w;
      row[m*V + vbase + f/NM] = f2h(x);
    }
  }
}

// ============================================================================
// K1 region 0: fp16 packed A-build (v_pk_mul_f16) + f16 MFMA.
// ============================================================================
DEVI void fwd_region0_f16(const unsigned short* lx, const uint4* __restrict__ bf,
                          int slot, int lane, f32x4 (&acc)[4][4])
{
  const int quad = lane>>4, col = lane&15;
  for (int u = slot; u < 128; u += 16) {
    unsigned xu2[4];
    #pragma unroll
    for (int mf = 0; mf < 4; ++mf) {
      unsigned s = lx[(mf*16+col)*136 + u];
      xu2[mf] = s | (s<<16);
    }
    #pragma unroll 1
    for (int c = 0; c < 4; ++c) {
      const int chunk = u*4 + c;
      uint4 bv[4];
      #pragma unroll
      for (int hf = 0; hf < 4; ++hf) bv[hf] = bf[(size_t)(chunk*4 + hf)*64 + lane];
      #pragma unroll
      for (int mf = 0; mf < 4; ++mf) {
        const uint4 xq = *reinterpret_cast<const uint4*>(lx + (mf*16+col)*136 + c*32 + quad*8);
        uint4 afq;
        afq.x = pkmul(xu2[mf], xq.x);
        afq.y = pkmul(xu2[mf], xq.y);
        afq.z = pkmul(xu2[mf], xq.z);
        afq.w = pkmul(xu2[mf], xq.w);
        #pragma unroll
        for (int hf = 0; hf < 4; ++hf)
          acc[mf][hf] = mfma16h(as_f16(afq), as_f16(bv[hf]), acc[mf][hf]);
      }
    }
  }
}

// ============================================================================
// K1 regions 1/2: f16 A-build via v_fma_mix_f32 + v_cvt_pkrtz + f16 MFMA.
// (R10 lesson: the pk_mul/pk_fma m-major variant regresses — this flat
// fma_mix form pipelines better.)
// ============================================================================
template<int R>
DEVI void fwd_region_f16(const unsigned short* lx, const uint4* __restrict__ bf,
                         int slot, int lane, f32x4 (&acc)[4][4])
{
  constexpr int NM = RC<R>::NM;
  const int quad = lane>>4, col = lane&15;
  for (int u = slot; u < RC<R>::ROWS; u += 16) {
    #pragma unroll 1
    for (int c = 0; c < RC<R>::NCH; ++c) {
      const int chunk = RC<R>::CBASE + u*RC<R>::NCH + c;
      uint4 bv[4];
      #pragma unroll
      for (int hf = 0; hf < 4; ++hf) bv[hf] = bf[(size_t)(chunk*4 + hf)*64 + lane];
      #pragma unroll
      for (int mf = 0; mf < 4; ++mf) {
        const unsigned short* rowp = lx + (mf*16+col)*RC<R>::STRIDE;
        float xu[NM];
        #pragma unroll
        for (int m = 0; m < NM; ++m) xu[m] = h2f(rowp[u*NM + m]);
        uint4 xq[NM];
        const uint4* xp4 = reinterpret_cast<const uint4*>(rowp + (c*32 + quad*8)*NM);
        #pragma unroll
        for (int q = 0; q < NM; ++q) xq[q] = xp4[q];
        unsigned aw[4];
        #pragma unroll
        for (int jp = 0; jp < 4; ++jp) {
          float p0 = 0.f, p1 = 0.f;
          #pragma unroll
          for (int m = 0; m < NM; ++m) {
            const int e0 = (2*jp+0)*NM + m, e1 = (2*jp+1)*NM + m;
            const unsigned w0 = wsel4(xq, e0>>1);
            const unsigned w1v = wsel4(xq, e1>>1);
            p0 = (e0&1) ? fmix_hi(xu[m], w0,  p0) : fmix_lo(xu[m], w0,  p0);
            p1 = (e1&1) ? fmix_hi(xu[m], w1v, p1) : fmix_lo(xu[m], w1v, p1);
          }
          aw[jp] = pk_f16(p0, p1);
        }
        uint4 afq; afq.x = aw[0]; afq.y = aw[1]; afq.z = aw[2]; afq.w = aw[3];
        #pragma unroll
        for (int hf = 0; hf < 4; ++hf)
          acc[mf][hf] = mfma16h(as_f16(afq), as_f16(bv[hf]), acc[mf][hf]);
      }
    }
  }
}

__global__ __launch_bounds__(256,2) void k_fwd(const float* __restrict__ t,
                                               const uint4* __restrict__ bfwd,
                                               float* __restrict__ hpre)
{
  __shared__ __align__(16) unsigned char smem[25600];  // max x-tile (r1); red[16KB] aliases
  unsigned short* lx = (unsigned short*)smem;
  const int nb = blockIdx.x*64;
  const int wv = threadIdx.x>>6, lane = threadIdx.x&63;
  const int slot = blockIdx.y*4 + wv;
  const int quad = lane>>4, col = lane&15;

  f32x4 acc[4][4];
  #pragma unroll
  for (int a = 0; a < 4; ++a)
    #pragma unroll
    for (int b = 0; b < 4; ++b) acc[a][b] = (f32x4){0.f,0.f,0.f,0.f};

  load_tile<0,true>(t, nb, lx); __syncthreads();
  fwd_region0_f16(lx, bfwd, slot, lane, acc); __syncthreads();
  load_tile<1,true>(t, nb, lx); __syncthreads();
  fwd_region_f16<1>(lx, bfwd, slot, lane, acc); __syncthreads();
  load_tile<2,true>(t, nb, lx); __syncthreads();
  fwd_region_f16<2>(lx, bfwd, slot, lane, acc); __syncthreads();

  float* red = (float*)smem;                 // 64x64 f32 = 16 KB
  for (int tw = 0; tw < 4; ++tw) {
    if (wv == tw) {
      #pragma unroll
      for (int mf = 0; mf < 4; ++mf)
        #pragma unroll
        for (int hf = 0; hf < 4; ++hf)
          #pragma unroll
          for (int rr = 0; rr < 4; ++rr) {
            int idx = (mf*16 + quad*4 + rr)*64 + hf*16 + col;
            if (tw == 0) red[idx] = acc[mf][hf][rr]; else red[idx] += acc[mf][hf][rr];
          }
    }
    __syncthreads();
  }
  float* hp = hpre + (size_t)blockIdx.y*NSAMP*64;
  for (int i = threadIdx.x; i < 4096; i += 256)
    hp[(size_t)(nb + (i>>6))*64 + (i&63)] = red[i];
}

// ============================================================================
// K2: MLP fwd + bwd.  16 samples/block, 1024 blocks.
// ============================================================================
__global__ __launch_bounds__(256) void k_mlp(
    const float* __restrict__ hpre,
    const float* __restrict__ w1, const float* __restrict__ b1,
    const float* __restrict__ w2, const float* __restrict__ b2,
    const float* __restrict__ w3, const float* __restrict__ b3,
    const float* __restrict__ w1t, const float* __restrict__ w2t, const float* __restrict__ w3t,
    float* __restrict__ xout, unsigned short* __restrict__ dhb)
{
  constexpr int SB  = 16;          // samples per block
  constexpr int LDW = 68;          // padded row stride (floats)
  __shared__ float Hs [SB*LDW];    // h rows; reused as g1 staging in phase D
  __shared__ float Bh1[SB*LDW];
  __shared__ float Bh2[SB*LDW];
  __shared__ float Bg2[SB*LDW];
  __shared__ unsigned short Bsp1[SB*LDW];
  const int n  = threadIdx.x & 15;       // sample within block
  const int g  = threadIdx.x >> 4;       // j-group [0,16)
  const int jb = g*4;                    // 4 consecutive j's per thread
  const int nb = blockIdx.x*SB;
  const size_t row = (size_t)(nb + n)*64;
  const size_t base = (size_t)nb*64;

  // stage h = sum of 4 hpre slices (SB*64 = 1024 elems, coalesced)
  for (int idx = threadIdx.x; idx < SB*64; idx += 256) {
    float s = hpre[base + idx]
            + hpre[(size_t)NSAMP*64   + base + idx]
            + hpre[(size_t)2*NSAMP*64 + base + idx]
            + hpre[(size_t)3*NSAMP*64 + base + idx];
    Hs[(idx>>6)*LDW + (idx&63)] = s;
  }

  // dh2r[jj] = row-sum of w3 (upstream grad of xout is ones)
  float dh2r[4];
  #pragma unroll
  for (int jj = 0; jj < 4; ++jj) {
    const float4* wr = reinterpret_cast<const float4*>(w3 + (jb+jj)*64);
    float s = 0.f;
    #pragma unroll
    for (int z4 = 0; z4 < 16; ++z4) { float4 v = wr[z4]; s += v.x; s += v.y; s += v.z; s += v.w; }
    dh2r[jj] = s;
  }
  __syncthreads();

  float hrow[64];
  #pragma unroll
  for (int i4 = 0; i4 < 16; ++i4) {
    float4 v = *reinterpret_cast<const float4*>(&Hs[n*LDW + i4*4]);
    hrow[i4*4+0]=v.x; hrow[i4*4+1]=v.y; hrow[i4*4+2]=v.z; hrow[i4*4+3]=v.w;
  }

  // ---- layer 1 fwd ----
  {
    float h1v[4], spv[4];
    #pragma unroll
    for (int jj = 0; jj < 4; ++jj) {
      const int j = jb + jj;
      float a = b1[j];
      const float4* wr = reinterpret_cast<const float4*>(w1t + j*64);
      #pragma unroll
      for (int i4 = 0; i4 < 16; ++i4) {
        float4 wv = wr[i4];
        a += hrow[i4*4+0]*wv.x; a += hrow[i4*4+1]*wv.y;
        a += hrow[i4*4+2]*wv.z; a += hrow[i4*4+3]*wv.w;
      }
      float sg = 1.f/(1.f + __expf(-a));
      h1v[jj] = a*sg;
      spv[jj] = sg*(1.f + a*(1.f-sg));
    }
    float4 o; o.x=h1v[0]; o.y=h1v[1]; o.z=h1v[2]; o.w=h1v[3];
    *reinterpret_cast<float4*>(&Bh1[n*LDW + jb]) = o;
    ushort4 us; us.x=f2b(spv[0]); us.y=f2b(spv[1]); us.z=f2b(spv[2]); us.w=f2b(spv[3]);
    *reinterpret_cast<ushort4*>(&Bsp1[n*LDW + jb]) = us;
  }
  __syncthreads();

  // ---- layer 2 fwd ----
  float h1row[64];
  #pragma unroll
  for (int i4 = 0; i4 < 16; ++i4) {
    float4 v = *reinterpret_cast<const float4*>(&Bh1[n*LDW + i4*4]);
    h1row[i4*4+0]=v.x; h1row[i4*4+1]=v.y; h1row[i4*4+2]=v.z; h1row[i4*4+3]=v.w;
  }
  {
    float h2v[4], g2v[4];
    #pragma unroll
    for (int jj = 0; jj < 4; ++jj) {
      const int j = jb + jj;
      float a = b2[j];
      const float4* wr = reinterpret_cast<const float4*>(w2t + j*64);
      #pragma unroll
      for (int i4 = 0; i4 < 16; ++i4) {
        float4 wv = wr[i4];
        a += h1row[i4*4+0]*wv.x; a += h1row[i4*4+1]*wv.y;
        a += h1row[i4*4+2]*wv.z; a += h1row[i4*4+3]*wv.w;
      }
      float sg = 1.f/(1.f + __expf(-a));
      h2v[jj] = a*sg;
      g2v[jj] = dh2r[jj]*(sg*(1.f + a*(1.f-sg)));
    }
    float4 o; o.x=h2v[0]; o.y=h2v[1]; o.z=h2v[2]; o.w=h2v[3];
    *reinterpret_cast<float4*>(&Bh2[n*LDW + jb]) = o;
    float4 p; p.x=g2v[0]; p.y=g2v[1]; p.z=g2v[2]; p.w=g2v[3];
    *reinterpret_cast<float4*>(&Bg2[n*LDW + jb]) = p;
  }
  __syncthreads();

  // ---- layer 3 fwd ----
  {
    float h2row[64];
    #pragma unroll
    for (int i4 = 0; i4 < 16; ++i4) {
      float4 v = *reinterpret_cast<const float4*>(&Bh2[n*LDW + i4*4]);
      h2row[i4*4+0]=v.x; h2row[i4*4+1]=v.y; h2row[i4*4+2]=v.z; h2row[i4*4+3]=v.w;
    }
    float xo[4];
    #pragma unroll
    for (int jj = 0; jj < 4; ++jj) {
      const int j = jb + jj;
      float a = b3[j];
      const float4* wr = reinterpret_cast<const float4*>(w3t + j*64);
      #pragma unroll
      for (int i4 = 0; i4 < 16; ++i4) {
        float4 wv = wr[i4];
        a += h2row[i4*4+0]*wv.x; a += h2row[i4*4+1]*wv.y;
        a += h2row[i4*4+2]*wv.z; a += h2row[i4*4+3]*wv.w;
      }
      xo[jj] = a;
    }
    float4 o; o.x=xo[0]; o.y=xo[1]; o.z=xo[2]; o.w=xo[3];
    *reinterpret_cast<float4*>(&xout[row + jb]) = o;
  }

  // ---- bwd layer 2: g1 = (g2 @ w2^T) * sp1 ----
  {
    float g2row[64];
    #pragma unroll
    for (int i4 = 0; i4 < 16; ++i4) {
      float4 v = *reinterpret_cast<const float4*>(&Bg2[n*LDW + i4*4]);
      g2row[i4*4+0]=v.x; g2row[i4*4+1]=v.y; g2row[i4*4+2]=v.z; g2row[i4*4+3]=v.w;
    }
    float g1v[4];
    #pragma unroll
    for (int jj = 0; jj < 4; ++jj) {
      const int i = jb + jj;
      float a = 0.f;
      const float4* wr = reinterpret_cast<const float4*>(w2 + i*64);
      #pragma unroll
      for (int z4 = 0; z4 < 16; ++z4) {
        float4 wv = wr[z4];
        a += g2row[z4*4+0]*wv.x; a += g2row[z4*4+1]*wv.y;
        a += g2row[z4*4+2]*wv.z; a += g2row[z4*4+3]*wv.w;
      }
      g1v[jj] = a * b2f(Bsp1[n*LDW + i]);
    }
    float4 o; o.x=g1v[0]; o.y=g1v[1]; o.z=g1v[2]; o.w=g1v[3];
    *reinterpret_cast<float4*>(&Hs[n*LDW + jb]) = o;
  }
  __syncthreads();

  // ---- bwd layer 1: dh = g1 @ w1^T -> dhb (bf16) ----
  {
    float g1row[64];
    #pragma unroll
    for (int i4 = 0; i4 < 16; ++i4) {
      float4 v = *reinterpret_cast<const float4*>(&Hs[n*LDW + i4*4]);
      g1row[i4*4+0]=v.x; g1row[i4*4+1]=v.y; g1row[i4*4+2]=v.z; g1row[i4*4+3]=v.w;
    }
    float dv[4];
    #pragma unroll
    for (int jj = 0; jj < 4; ++jj) {
      const int i = jb + jj;
      float a = 0.f;
      const float4* wr = reinterpret_cast<const float4*>(w1 + i*64);
      #pragma unroll
      for (int z4 = 0; z4 < 16; ++z4) {
        float4 wv = wr[z4];
        a += g1row[z4*4+0]*wv.x; a += g1row[z4*4+1]*wv.y;
        a += g1row[z4*4+2]*wv.z; a += g1row[z4*4+3]*wv.w;
      }
      dv[jj] = a;
    }
    ushort4 us; us.x=f2b(dv[0]); us.y=f2b(dv[1]); us.z=f2b(dv[2]); us.w=f2b(dv[3]);
    *reinterpret_cast<ushort4*>(&dhb[row + jb]) = us;
  }
}

// ============================================================================
// K3: backward TP.  MFMA path (bbwd x dh, both bf16); VALU v-contraction via
// v_dot2_f32_f16 against the m-major BST-padded fp16 x-tile.
// launch_bounds(256,2): tighter bounds spill (R5/R8).
// ============================================================================
template<int R>
DEVI void bwd_region(const unsigned short* lx, const uint4 (&bq)[4][2],
                     const uint4* __restrict__ ba, int slot, int lane,
                     float* __restrict__ gws, int nb)
{
  constexpr int NM = RC<R>::NM;
  constexpr int V  = RC<R>::COLS / NM;   // 128 / 64 / 32
  const int quad = lane>>4, col = lane&15;
  for (int u = slot; u < RC<R>::ROWS; u += 16) {
    float gacc[4][NM];
    #pragma unroll
    for (int nf = 0; nf < 4; ++nf)
      #pragma unroll
      for (int m = 0; m < NM; ++m) gacc[nf][m] = 0.f;

    #pragma unroll 1
    for (int c = 0; c < RC<R>::NCH; ++c) {
      uint4 aq[2][2];
      #pragma unroll
      for (int kf = 0; kf < 2; ++kf)
        #pragma unroll
        for (int kc = 0; kc < 2; ++kc) {
          int kb = RC<R>::KBASE + u*(2*RC<R>::NCH) + c*2 + kf;
          aq[kf][kc] = ba[(size_t)(kb*2+kc)*64 + lane];
        }
      #pragma unroll
      for (int kf = 0; kf < 2; ++kf) {
        const int v0 = c*32 + kf*16 + quad*4;
        #pragma unroll
        for (int nf = 0; nf < 4; ++nf) {
          f32x4 a4 = (f32x4){0.f,0.f,0.f,0.f};
          a4 = mfma16(as_bf(aq[kf][0]), as_bf(bq[nf][0]), a4);
          a4 = mfma16(as_bf(aq[kf][1]), as_bf(bq[nf][1]), a4);
          const unsigned pA = pk_f16(a4[0], a4[1]);   // {a4[0], a4[1]} f16
          const unsigned pB = pk_f16(a4[2], a4[3]);   // {a4[2], a4[3]} f16
          const unsigned short* xp = lx + (nf*16+col)*RC<R>::BST;
          #pragma unroll
          for (int m = 0; m < NM; ++m) {
            const uint2 xw = *reinterpret_cast<const uint2*>(xp + m*V + v0);
            gacc[nf][m] = fdot2(pA, xw.x, fdot2(pB, xw.y, gacc[nf][m]));
          }
        }
      }
    }
    #pragma unroll
    for (int nf = 0; nf < 4; ++nf)
      #pragma unroll
      for (int m = 0; m < NM; ++m) {
        float v = gacc[nf][m];
        v += __shfl_down(v, 32, 64);
        v += __shfl_down(v, 16, 64);
        if (lane < 16)
          gws[(size_t)(RC<R>::OUT + u*NM + m)*NSAMP + nb + nf*16 + lane] = v;
      }
  }
}

__global__ __launch_bounds__(256,2) void k_bwd(const float* __restrict__ t,
                                               const uint4* __restrict__ bbwd,
                                               const unsigned short* __restrict__ dh,
                                               float* __restrict__ gws)
{
  __shared__ __align__(16) unsigned char smem[26112];  // max BST tile (r1: 64*204*2)
  unsigned short* lx = (unsigned short*)smem;
  const int nb = blockIdx.x*64;
  const int wv = threadIdx.x>>6, lane = threadIdx.x&63;
  const int slot = blockIdx.y*4 + wv;
  const int cl = lane&15, qd = lane>>4;

  uint4 bq[4][2];   // resident dh B-frags: B[h][n]
  #pragma unroll
  for (int nf = 0; nf < 4; ++nf)
    #pragma unroll
    for (int kc = 0; kc < 2; ++kc)
      bq[nf][kc] = *reinterpret_cast<const uint4*>(dh + (size_t)(nb + nf*16 + cl)*64 + kc*32 + qd*8);

  load_tile_bwd<0>(t, nb, lx); __syncthreads();
  bwd_region<0>(lx, bq, bbwd, slot, lane, gws, nb); __syncthreads();
  load_tile_bwd<1>(t, nb, lx); __syncthreads();
  bwd_region<1>(lx, bq, bbwd, slot, lane, gws, nb); __syncthreads();
  load_tile_bwd<2>(t, nb, lx); __syncthreads();
  bwd_region<2>(lx, bq, bbwd, slot, lane, gws, nb);
}

// ============================================================================
// K4: transpose gws[480][16384] -> y[16384][480], coalesced both sides.
// ============================================================================
__global__ __launch_bounds__(256) void k_tr(const float* __restrict__ gws,
                                            float* __restrict__ y)
{
  __shared__ float tile[32][481];
  const int n0 = blockIdx.x*32;
  for (int idx = threadIdx.x; idx < 480*8; idx += 256) {
    int c = idx >> 3, i4 = idx & 7;
    float4 v = reinterpret_cast<const float4*>(gws + (size_t)c*NSAMP + n0)[i4];
    tile[i4*4+0][c] = v.x; tile[i4*4+1][c] = v.y;
    tile[i4*4+2][c] = v.z; tile[i4*4+3][c] = v.w;
  }
  __syncthreads();
  for (int idx = threadIdx.x; idx < 32*120; idx += 256) {
    int s = idx/120, c4 = idx%120;
    float4 v = { tile[s][c4*4+0], tile[s][c4*4+1], tile[s][c4*4+2], tile[s][c4*4+3] };
    reinterpret_cast<float4*>(y + (size_t)(n0+s)*TDIM)[c4] = v;
  }
}

// ============================================================================
extern "C" void kernel_launch(void* const* d_in, const int* in_sizes, int n_in,
                              void* d_out, int out_size, void* d_ws, size_t ws_size,
                              hipStream_t stream) {
  (void)in_sizes; (void)n_in; (void)out_size; (void)ws_size;
  const float* t  = (const float*)d_in[0];
  const float* W0 = (const float*)d_in[1];
  const float* W1 = (const float*)d_in[2];
  const float* W2 = (const float*)d_in[3];
  const float* w1 = (const float*)d_in[4];
  const float* b1 = (const float*)d_in[5];
  const float* w2 = (const float*)d_in[6];
  const float* b2 = (const float*)d_in[7];
  const float* w3 = (const float*)d_in[8];
  const float* b3 = (const float*)d_in[9];

  char* ws = (char*)d_ws;
  float*          gws  = (float*)(ws + O_GWS);
  unsigned short* bfwd = (unsigned short*)(ws + O_BFWD);
  unsigned short* bbwd = (unsigned short*)(ws + O_BBWD);
  float*          hpre = (float*)(ws + O_HPRE);
  unsigned short* dhb  = (unsigned short*)(ws + O_DH);
  float*          w1t  = (float*)(ws + O_W1T);
  float*          w2t  = (float*)(ws + O_W2T);
  float*          w3t  = (float*)(ws + O_W3T);

  float* xout = (float*)d_out;
  float* y    = (float*)d_out + (size_t)NSAMP*64;

  k_prep<<<dim3(5376), dim3(256), 0, stream>>>(W0, W1, W2, w1, w2, w3,
                                               bfwd, bbwd, w1t, w2t, w3t);
  k_fwd <<<dim3(256,4), dim3(256), 0, stream>>>(t, (const uint4*)bfwd, hpre);
  k_mlp <<<dim3(1024), dim3(256), 0, stream>>>(hpre, w1, b1, w2, b2, w3, b3,
                                               w1t, w2t, w3t, xout, dhb);
  k_bwd <<<dim3(256,4), dim3(256), 0, stream>>>(t, (const uint4*)bbwd, dhb, gws);
  k_tr  <<<dim3(512),   dim3(256), 0, stream>>>(gws, y);
}